// Round 1
// baseline (204.248 us; speedup 1.0000x reference)
//
#include <hip/hip_runtime.h>
#include <hip/hip_bf16.h>

// GQA prefill: B=2 T=2048 DM=768 H=12 HKV=4 DH=64 GROUPS=3 WIN=512 GLB=64
// Pipeline: x->bf16, W->W^T bf16, rope table; Q/K/V proj GEMMs (rope fused,
// V stored transposed); flash attention with sparse mask; out GEMM (f32 out).

typedef __attribute__((ext_vector_type(8))) short bf16x8;
typedef __attribute__((ext_vector_type(4))) float f32x4;
typedef __attribute__((ext_vector_type(4))) unsigned short u16x4;

#define MFMA16x16x32 __builtin_amdgcn_mfma_f32_16x16x32_bf16

constexpr int BB = 2, TT = 2048, DM = 768, HH = 12, HKV = 4, DH = 64;
constexpr int WIN = 512, GLB = 64;

__device__ __forceinline__ unsigned short f2b(float f) {
    union { float f; unsigned int u; } v; v.f = f;
    unsigned int r = v.u + 0x7fffu + ((v.u >> 16) & 1u);
    return (unsigned short)(r >> 16);
}

__global__ __launch_bounds__(256) void k_convert_x(const float* __restrict__ x,
                                                   unsigned short* __restrict__ xb, int n4) {
    int i = blockIdx.x * 256 + threadIdx.x;
    if (i < n4) {
        float4 v = ((const float4*)x)[i];
        u16x4 o;
        o.x = f2b(v.x); o.y = f2b(v.y); o.z = f2b(v.z); o.w = f2b(v.w);
        ((u16x4*)xb)[i] = o;
    }
}

__global__ __launch_bounds__(256) void k_transpose_w(const float* __restrict__ w,
                                                     unsigned short* __restrict__ wt,
                                                     int K, int N) {
    int i = blockIdx.x * 256 + threadIdx.x;
    if (i < K * N) {
        int k = i / N, n = i - k * N;
        wt[n * K + k] = f2b(w[i]);
    }
}

__global__ __launch_bounds__(256) void k_rope(float2* __restrict__ tab) {
    int i = blockIdx.x * 256 + threadIdx.x; // T*32
    int t = i >> 5, p = i & 31;
    float inv = __expf(-(float)p * (9.210340371976184f / 32.0f)); // 10000^(-p/32)
    float ang = (float)t * inv;
    float s, c;
    __sincosf(ang, &s, &c); // fast path ok? use precise below instead
    c = cosf(ang); s = sinf(ang);
    tab[i] = make_float2(c, s);
}

// MODE: 0 = Q proj (rope, [B,H,T,DH]), 1 = K proj (rope, [B,HKV,T,DH]),
//       2 = V proj (transposed store [B,HKV,DH,T]), 3 = out GEMM (f32 store)
template <int MODE>
__global__ __launch_bounds__(256) void k_gemm(const unsigned short* __restrict__ A,
                                              const unsigned short* __restrict__ Bt,
                                              unsigned short* __restrict__ out_b,
                                              float* __restrict__ out_f,
                                              const float2* __restrict__ rope) {
    const int wave = threadIdx.x >> 6, lane = threadIdx.x & 63;
    const int quad = lane >> 4, col = lane & 15;
    const int m0 = blockIdx.x * 64 + wave * 16;
    const int n0 = blockIdx.y * 64;

    const unsigned short* ap = A + (size_t)(m0 + col) * DM + quad * 8;
    const unsigned short* bp = Bt + (size_t)(n0 + col) * DM + quad * 8;

    f32x4 acc[4] = {f32x4{0,0,0,0}, f32x4{0,0,0,0}, f32x4{0,0,0,0}, f32x4{0,0,0,0}};

    #pragma unroll 4
    for (int k = 0; k < DM; k += 32) {
        bf16x8 a = *(const bf16x8*)(ap + k);
        #pragma unroll
        for (int nt = 0; nt < 4; ++nt) {
            bf16x8 b = *(const bf16x8*)(bp + nt * 16 * DM + k);
            acc[nt] = MFMA16x16x32(a, b, acc[nt], 0, 0, 0);
        }
    }

    if (MODE == 3) {
        #pragma unroll
        for (int nt = 0; nt < 4; ++nt)
            #pragma unroll
            for (int r = 0; r < 4; ++r) {
                int m = m0 + quad * 4 + r;
                out_f[(size_t)m * DM + n0 + nt * 16 + col] = acc[nt][r];
            }
        return;
    }
    if (MODE == 2) {
        int b = m0 >> 11; // m0 / 2048
        #pragma unroll
        for (int nt = 0; nt < 4; ++nt)
            #pragma unroll
            for (int r = 0; r < 4; ++r) {
                int m = m0 + quad * 4 + r;
                int t = m & (TT - 1);
                int d = nt * 16 + col;
                out_b[((size_t)(b * HKV + blockIdx.y) * DH + d) * TT + t] = f2b(acc[nt][r]);
            }
        return;
    }
    // MODE 0/1: rope epilogue.  d = nt*16+col; pairs (d, d+32) are (nt, nt+2).
    {
        int b = m0 >> 11;
        int nheads = (MODE == 0) ? HH : HKV;
        #pragma unroll
        for (int r = 0; r < 4; ++r) {
            int m = m0 + quad * 4 + r;
            int t = m & (TT - 1);
            float2 cs0 = rope[t * 32 + col];        // p = col      (d<32 half: nt 0; partner nt 2)
            float2 cs1 = rope[t * 32 + 16 + col];   // p = 16+col   (nt 1; partner nt 3)
            float v0 = acc[0][r], v1 = acc[1][r], v2 = acc[2][r], v3 = acc[3][r];
            float o0 = v0 * cs0.x - v2 * cs0.y;
            float o1 = v1 * cs1.x - v3 * cs1.y;
            float o2 = v2 * cs0.x + v0 * cs0.y;
            float o3 = v3 * cs1.x + v1 * cs1.y;
            unsigned short* dst = out_b + ((size_t)(b * nheads + blockIdx.y) * TT + t) * DH + col;
            dst[0]  = f2b(o0);
            dst[16] = f2b(o1);
            dst[32] = f2b(o2);
            dst[48] = f2b(o3);
        }
    }
}

__global__ __launch_bounds__(256) void k_attn(const unsigned short* __restrict__ Q,
                                              const unsigned short* __restrict__ K,
                                              const unsigned short* __restrict__ Vt,
                                              unsigned short* __restrict__ AO) {
    __shared__ __align__(16) unsigned short plds[4][16 * 40]; // padded rows: 40 ushorts = 80B
    const int wave = threadIdx.x >> 6, lane = threadIdx.x & 63;
    const int quad = lane >> 4, col = lane & 15;
    const int bid = blockIdx.x;
    const int qb = bid & 31;
    const int bh = bid >> 5;       // 0..23
    const int h = bh % HH, b = bh / HH;
    const int hkv = h / 3;
    const int i0 = qb * 64 + wave * 16;

    const unsigned short* qbase = Q + ((size_t)(b * HH + h) * TT + i0 + col) * DH + quad * 8;
    bf16x8 qf0 = *(const bf16x8*)(qbase);
    bf16x8 qf1 = *(const bf16x8*)(qbase + 32);

    const unsigned short* kbase = K + (size_t)(b * HKV + hkv) * TT * DH;
    const unsigned short* vbase = Vt + (size_t)(b * HKV + hkv) * DH * TT;

    float m_run[4] = {-INFINITY, -INFINITY, -INFINITY, -INFINITY};
    float l_run[4] = {0.f, 0.f, 0.f, 0.f};
    f32x4 accO[4] = {f32x4{0,0,0,0}, f32x4{0,0,0,0}, f32x4{0,0,0,0}, f32x4{0,0,0,0}};

    const int maxjt = (i0 + 15) >> 5;
    const int wstart = i0 - (WIN - 1);

    for (int jti = 0; jti <= maxjt; ++jti) {
        int j0 = jti * 32;
        if (j0 >= GLB && (j0 + 31) < wstart) continue; // tile fully outside window & global

        const unsigned short* kp = kbase + (size_t)(j0 + col) * DH + quad * 8;
        bf16x8 k00 = *(const bf16x8*)(kp);
        bf16x8 k01 = *(const bf16x8*)(kp + 32);
        bf16x8 k10 = *(const bf16x8*)(kp + 16 * DH);
        bf16x8 k11 = *(const bf16x8*)(kp + 16 * DH + 32);
        f32x4 s0 = {0, 0, 0, 0}, s1 = {0, 0, 0, 0};
        s0 = MFMA16x16x32(qf0, k00, s0, 0, 0, 0);
        s0 = MFMA16x16x32(qf1, k01, s0, 0, 0, 0);
        s1 = MFMA16x16x32(qf0, k10, s1, 0, 0, 0);
        s1 = MFMA16x16x32(qf1, k11, s1, 0, 0, 0);

        float sv0[4], sv1[4], pmax[4];
        #pragma unroll
        for (int r = 0; r < 4; ++r) {
            int i = i0 + quad * 4 + r;
            int ja = j0 + col;
            int jb2 = ja + 16;
            bool ok0 = (ja <= i) && (((i - ja) < WIN) || (ja < GLB));
            bool ok1 = (jb2 <= i) && (((i - jb2) < WIN) || (jb2 < GLB));
            sv0[r] = ok0 ? s0[r] * 0.125f : -INFINITY;
            sv1[r] = ok1 ? s1[r] * 0.125f : -INFINITY;
            pmax[r] = fmaxf(sv0[r], sv1[r]);
        }
        #pragma unroll
        for (int msk = 1; msk <= 8; msk <<= 1) {
            #pragma unroll
            for (int r = 0; r < 4; ++r)
                pmax[r] = fmaxf(pmax[r], __shfl_xor(pmax[r], msk));
        }

        float corr[4], psum[4], p0[4], p1[4];
        #pragma unroll
        for (int r = 0; r < 4; ++r) {
            float mn = fmaxf(m_run[r], pmax[r]);
            corr[r] = (mn == -INFINITY) ? 1.0f : __expf(m_run[r] - mn);
            m_run[r] = mn;
            p0[r] = (sv0[r] == -INFINITY) ? 0.0f : __expf(sv0[r] - mn);
            p1[r] = (sv1[r] == -INFINITY) ? 0.0f : __expf(sv1[r] - mn);
            psum[r] = p0[r] + p1[r];
        }
        #pragma unroll
        for (int msk = 1; msk <= 8; msk <<= 1) {
            #pragma unroll
            for (int r = 0; r < 4; ++r)
                psum[r] += __shfl_xor(psum[r], msk);
        }
        #pragma unroll
        for (int r = 0; r < 4; ++r)
            l_run[r] = l_run[r] * corr[r] + psum[r];

        // P -> LDS (transpose to A-fragment layout), rescale O
        unsigned short* pw = plds[wave];
        #pragma unroll
        for (int r = 0; r < 4; ++r) {
            pw[(quad * 4 + r) * 40 + col] = f2b(p0[r]);
            pw[(quad * 4 + r) * 40 + 16 + col] = f2b(p1[r]);
        }
        #pragma unroll
        for (int dt = 0; dt < 4; ++dt) {
            #pragma unroll
            for (int r = 0; r < 4; ++r)
                accO[dt][r] *= corr[r];
        }
        bf16x8 pfrag = *(const bf16x8*)&pw[col * 40 + quad * 8];
        const unsigned short* vp = vbase + (size_t)col * TT + j0 + quad * 8;
        #pragma unroll
        for (int dt = 0; dt < 4; ++dt) {
            bf16x8 vf = *(const bf16x8*)(vp + (size_t)dt * 16 * TT);
            accO[dt] = MFMA16x16x32(pfrag, vf, accO[dt], 0, 0, 0);
        }
    }

    #pragma unroll
    for (int dt = 0; dt < 4; ++dt) {
        #pragma unroll
        for (int r = 0; r < 4; ++r) {
            int t = i0 + quad * 4 + r;
            float o = accO[dt][r] / l_run[r];
            AO[((size_t)b * TT + t) * DM + h * DH + dt * 16 + col] = f2b(o);
        }
    }
}

extern "C" void kernel_launch(void* const* d_in, const int* in_sizes, int n_in,
                              void* d_out, int out_size, void* d_ws, size_t ws_size,
                              hipStream_t stream) {
    const float* x  = (const float*)d_in[0];
    const float* wq = (const float*)d_in[1];
    const float* wk = (const float*)d_in[2];
    const float* wv = (const float*)d_in[3];
    const float* wo = (const float*)d_in[4];
    float* out = (float*)d_out;

    char* ws = (char*)d_ws;
    size_t off = 0;
    auto alloc = [&](size_t bytes) -> void* {
        void* p = ws + off;
        off += (bytes + 255) & ~(size_t)255;
        return p;
    };
    const int M = BB * TT; // 4096
    unsigned short* xb  = (unsigned short*)alloc((size_t)M * DM * 2);
    unsigned short* wqT = (unsigned short*)alloc((size_t)DM * DM * 2);
    unsigned short* wkT = (unsigned short*)alloc((size_t)(HKV * DH) * DM * 2);
    unsigned short* wvT = (unsigned short*)alloc((size_t)(HKV * DH) * DM * 2);
    unsigned short* woT = (unsigned short*)alloc((size_t)DM * DM * 2);
    unsigned short* qb  = (unsigned short*)alloc((size_t)BB * HH * TT * DH * 2);
    unsigned short* kb  = (unsigned short*)alloc((size_t)BB * HKV * TT * DH * 2);
    unsigned short* vtb = (unsigned short*)alloc((size_t)BB * HKV * DH * TT * 2);
    unsigned short* ao  = (unsigned short*)alloc((size_t)M * DM * 2);
    float2* rope        = (float2*)alloc((size_t)TT * 32 * sizeof(float2));

    // prep
    int n4 = M * DM / 4;
    k_convert_x<<<(n4 + 255) / 256, 256, 0, stream>>>(x, xb, n4);
    k_transpose_w<<<(DM * DM + 255) / 256, 256, 0, stream>>>(wq, wqT, DM, DM);
    k_transpose_w<<<(DM * HKV * DH + 255) / 256, 256, 0, stream>>>(wk, wkT, DM, HKV * DH);
    k_transpose_w<<<(DM * HKV * DH + 255) / 256, 256, 0, stream>>>(wv, wvT, DM, HKV * DH);
    k_transpose_w<<<(DM * DM + 255) / 256, 256, 0, stream>>>(wo, woT, DM, DM);
    k_rope<<<(TT * 32) / 256, 256, 0, stream>>>(rope);

    // projections
    k_gemm<0><<<dim3(M / 64, HH), 256, 0, stream>>>(xb, wqT, qb, nullptr, rope);
    k_gemm<1><<<dim3(M / 64, HKV), 256, 0, stream>>>(xb, wkT, kb, nullptr, rope);
    k_gemm<2><<<dim3(M / 64, HKV), 256, 0, stream>>>(xb, wvT, vtb, nullptr, rope);

    // attention
    k_attn<<<BB * HH * (TT / 64), 256, 0, stream>>>(qb, kb, vtb, ao);

    // output projection
    k_gemm<3><<<dim3(M / 64, HH), 256, 0, stream>>>(ao, woT, nullptr, out, rope);
}

// Round 2
// 157.798 us; speedup vs baseline: 1.2944x; 1.2944x over previous
//
#include <hip/hip_runtime.h>
#include <hip/hip_bf16.h>

// GQA prefill: B=2 T=2048 DM=768 H=12 HKV=4 DH=64 WIN=512 GLB=64
// 5 launches: prep(convert+rope) | transpose-all | fused QKV GEMM (rope fused,
// V transposed) | flash attn (KVBLK=64, defer-max, deferred l-reduce) | out GEMM.

typedef __attribute__((ext_vector_type(8))) short bf16x8;
typedef __attribute__((ext_vector_type(4))) float f32x4;
typedef __attribute__((ext_vector_type(4))) unsigned short u16x4;

#define MFMA __builtin_amdgcn_mfma_f32_16x16x32_bf16

constexpr int BB = 2, TT = 2048, DM = 768, HH = 12, HKV = 4, DH = 64;
constexpr int WIN = 512, GLB = 64;
constexpr float SC2 = 0.18033688011112042f; // 0.125 * log2(e)

__device__ __forceinline__ unsigned short f2b(float f) {
    union { float f; unsigned int u; } v; v.f = f;
    unsigned int r = v.u + 0x7fffu + ((v.u >> 16) & 1u);
    return (unsigned short)(r >> 16);
}

// ---------- prep: x -> bf16 (blocks 0..3071), rope table (blocks 3072..3327)
__global__ __launch_bounds__(256) void k_prep(const float* __restrict__ x,
                                              unsigned short* __restrict__ xb,
                                              float2* __restrict__ rope) {
    int bid = blockIdx.x, tid = threadIdx.x;
    if (bid < 3072) {
        int i = bid * 256 + tid;
        float4 v = ((const float4*)x)[i];
        u16x4 o; o.x = f2b(v.x); o.y = f2b(v.y); o.z = f2b(v.z); o.w = f2b(v.w);
        ((u16x4*)xb)[i] = o;
    } else {
        int i = (bid - 3072) * 256 + tid;  // T*32
        int t = i >> 5, p = i & 31;
        float inv = exp2f(-(float)p * (13.287712379549449f / 32.0f)); // 10000^(-p/32)
        float ang = (float)t * inv;
        rope[i] = make_float2(cosf(ang), sinf(ang));
    }
}

// ---------- transpose all weights: f32 [K][N] -> bf16 [N][K], LDS 32x32 tiles
__global__ __launch_bounds__(256) void k_tw(const float* __restrict__ wq,
                                            const float* __restrict__ wk,
                                            const float* __restrict__ wv,
                                            const float* __restrict__ wo,
                                            unsigned short* __restrict__ wqT,
                                            unsigned short* __restrict__ wkT,
                                            unsigned short* __restrict__ wvT,
                                            unsigned short* __restrict__ woT) {
    __shared__ float t[32][33];
    int bid = blockIdx.x;
    const float* src; unsigned short* dst; int N, tile;
    if (bid < 576)      { src = wq; dst = wqT; N = 768; tile = bid; }
    else if (bid < 768) { src = wk; dst = wkT; N = 256; tile = bid - 576; }
    else if (bid < 960) { src = wv; dst = wvT; N = 256; tile = bid - 768; }
    else                { src = wo; dst = woT; N = 768; tile = bid - 960; }
    int ntiles = N / 32;
    int k0 = (tile / ntiles) * 32, n0 = (tile % ntiles) * 32;
    int tx = threadIdx.x & 31, ty = threadIdx.x >> 5;
    #pragma unroll
    for (int e = 0; e < 4; ++e) {
        int r = ty + e * 8;
        t[r][tx] = src[(size_t)(k0 + r) * N + n0 + tx];
    }
    __syncthreads();
    #pragma unroll
    for (int e = 0; e < 4; ++e) {
        int r = ty + e * 8;
        dst[(size_t)(n0 + r) * DM + k0 + tx] = f2b(t[tx][r]);
    }
}

// ---------- fused QKV projection GEMM: y<12 Q(rope), y<16 K(rope), else V(transposed)
__global__ __launch_bounds__(256) void k_qkv(const unsigned short* __restrict__ xb,
                                             const unsigned short* __restrict__ wqT,
                                             const unsigned short* __restrict__ wkT,
                                             const unsigned short* __restrict__ wvT,
                                             unsigned short* __restrict__ qb,
                                             unsigned short* __restrict__ kb,
                                             unsigned short* __restrict__ vtb,
                                             const float2* __restrict__ rope) {
    const int wave = threadIdx.x >> 6, lane = threadIdx.x & 63;
    const int quad = lane >> 4, col = lane & 15;
    const int y = blockIdx.y;
    const int m0 = blockIdx.x * 128 + wave * 32;
    int mode, hl;
    const unsigned short* Bt;
    if (y < 12)      { mode = 0; hl = y;      Bt = wqT + (size_t)hl * 64 * DM; }
    else if (y < 16) { mode = 1; hl = y - 12; Bt = wkT + (size_t)hl * 64 * DM; }
    else             { mode = 2; hl = y - 16; Bt = wvT + (size_t)hl * 64 * DM; }

    const unsigned short* ap = xb + (size_t)(m0 + col) * DM + quad * 8;
    const unsigned short* bp = Bt + (size_t)col * DM + quad * 8;

    f32x4 acc[2][4];
    #pragma unroll
    for (int rt = 0; rt < 2; ++rt)
        #pragma unroll
        for (int nt = 0; nt < 4; ++nt) acc[rt][nt] = f32x4{0.f, 0.f, 0.f, 0.f};

    #pragma unroll 4
    for (int k = 0; k < DM; k += 32) {
        bf16x8 a0 = *(const bf16x8*)(ap + k);
        bf16x8 a1 = *(const bf16x8*)(ap + 16 * DM + k);
        #pragma unroll
        for (int nt = 0; nt < 4; ++nt) {
            bf16x8 b = *(const bf16x8*)(bp + (size_t)nt * 16 * DM + k);
            acc[0][nt] = MFMA(a0, b, acc[0][nt], 0, 0, 0);
            acc[1][nt] = MFMA(a1, b, acc[1][nt], 0, 0, 0);
        }
    }

    if (mode == 2) {
        int b = m0 >> 11;
        #pragma unroll
        for (int nt = 0; nt < 4; ++nt)
            #pragma unroll
            for (int rt = 0; rt < 2; ++rt)
                #pragma unroll
                for (int r = 0; r < 4; ++r) {
                    int m = m0 + rt * 16 + quad * 4 + r;
                    int t = m & (TT - 1);
                    int d = nt * 16 + col;
                    vtb[((size_t)(b * HKV + hl) * DH + d) * TT + t] = f2b(acc[rt][nt][r]);
                }
        return;
    }
    int nheads = (mode == 0) ? HH : HKV;
    unsigned short* ob = (mode == 0) ? qb : kb;
    #pragma unroll
    for (int rt = 0; rt < 2; ++rt)
        #pragma unroll
        for (int r = 0; r < 4; ++r) {
            int m = m0 + rt * 16 + quad * 4 + r;
            int t = m & (TT - 1);
            int b = m >> 11;
            float2 cs0 = rope[t * 32 + col];
            float2 cs1 = rope[t * 32 + 16 + col];
            float v0 = acc[rt][0][r], v1 = acc[rt][1][r], v2 = acc[rt][2][r], v3 = acc[rt][3][r];
            unsigned short* dst = ob + ((size_t)(b * nheads + hl) * TT + t) * DH + col;
            dst[0]  = f2b(v0 * cs0.x - v2 * cs0.y);
            dst[16] = f2b(v1 * cs1.x - v3 * cs1.y);
            dst[32] = f2b(v2 * cs0.x + v0 * cs0.y);
            dst[48] = f2b(v3 * cs1.x + v1 * cs1.y);
        }
}

// ---------- output projection GEMM (f32 out)
__global__ __launch_bounds__(256) void k_out(const unsigned short* __restrict__ ao,
                                             const unsigned short* __restrict__ woT,
                                             float* __restrict__ out) {
    const int wave = threadIdx.x >> 6, lane = threadIdx.x & 63;
    const int quad = lane >> 4, col = lane & 15;
    const int m0 = blockIdx.x * 128 + wave * 32;
    const int n0 = blockIdx.y * 64;

    const unsigned short* ap = ao + (size_t)(m0 + col) * DM + quad * 8;
    const unsigned short* bp = woT + (size_t)(n0 + col) * DM + quad * 8;

    f32x4 acc[2][4];
    #pragma unroll
    for (int rt = 0; rt < 2; ++rt)
        #pragma unroll
        for (int nt = 0; nt < 4; ++nt) acc[rt][nt] = f32x4{0.f, 0.f, 0.f, 0.f};

    #pragma unroll 4
    for (int k = 0; k < DM; k += 32) {
        bf16x8 a0 = *(const bf16x8*)(ap + k);
        bf16x8 a1 = *(const bf16x8*)(ap + 16 * DM + k);
        #pragma unroll
        for (int nt = 0; nt < 4; ++nt) {
            bf16x8 b = *(const bf16x8*)(bp + (size_t)nt * 16 * DM + k);
            acc[0][nt] = MFMA(a0, b, acc[0][nt], 0, 0, 0);
            acc[1][nt] = MFMA(a1, b, acc[1][nt], 0, 0, 0);
        }
    }
    #pragma unroll
    for (int rt = 0; rt < 2; ++rt)
        #pragma unroll
        for (int nt = 0; nt < 4; ++nt)
            #pragma unroll
            for (int r = 0; r < 4; ++r) {
                int m = m0 + rt * 16 + quad * 4 + r;
                out[(size_t)m * DM + n0 + nt * 16 + col] = acc[rt][nt][r];
            }
}

// ---------- flash attention tile: MASK 0=none, 1=causal-only (global tile), 2=window
template <int MASK>
__device__ __forceinline__ void attn_tile(int j0, int i0, int quad, int col,
                                          const unsigned short* __restrict__ kbase,
                                          const unsigned short* __restrict__ vbase,
                                          bf16x8 qf0, bf16x8 qf1, float* __restrict__ pw,
                                          float (&m_run)[4], float (&l_lane)[4],
                                          f32x4 (&accO)[4]) {
    const unsigned short* kp = kbase + (size_t)(j0 + col) * DH + quad * 8;
    bf16x8 kf0[4], kf1[4];
    #pragma unroll
    for (int f = 0; f < 4; ++f) {
        kf0[f] = *(const bf16x8*)(kp + (size_t)f * 16 * DH);
        kf1[f] = *(const bf16x8*)(kp + (size_t)f * 16 * DH + 32);
    }
    f32x4 s[4];
    #pragma unroll
    for (int f = 0; f < 4; ++f) s[f] = f32x4{0.f, 0.f, 0.f, 0.f};
    __builtin_amdgcn_s_setprio(1);
    #pragma unroll
    for (int f = 0; f < 4; ++f) {
        s[f] = MFMA(qf0, kf0[f], s[f], 0, 0, 0);
        s[f] = MFMA(qf1, kf1[f], s[f], 0, 0, 0);
    }
    __builtin_amdgcn_s_setprio(0);

    float mx[4] = {-3e30f, -3e30f, -3e30f, -3e30f};
    #pragma unroll
    for (int f = 0; f < 4; ++f)
        #pragma unroll
        for (int r = 0; r < 4; ++r) {
            float v = s[f][r];
            if (MASK == 1) {
                int i = i0 + quad * 4 + r, j = j0 + f * 16 + col;
                v = (j <= i) ? v : -3e30f;
            }
            if (MASK == 2) {
                int i = i0 + quad * 4 + r, j = j0 + f * 16 + col;
                v = ((unsigned)(i - j) < (unsigned)WIN) ? v : -3e30f;
            }
            s[f][r] = v;
            mx[r] = fmaxf(mx[r], v);
        }

    bool ok = (mx[0] <= m_run[0] + 44.f) && (mx[1] <= m_run[1] + 44.f) &&
              (mx[2] <= m_run[2] + 44.f) && (mx[3] <= m_run[3] + 44.f);
    if (!__all(ok)) {
        #pragma unroll
        for (int r = 0; r < 4; ++r) {
            float t = mx[r];
            t = fmaxf(t, __shfl_xor(t, 1));
            t = fmaxf(t, __shfl_xor(t, 2));
            t = fmaxf(t, __shfl_xor(t, 4));
            t = fmaxf(t, __shfl_xor(t, 8));
            float mn = fmaxf(m_run[r], t);
            float corr = exp2f((m_run[r] - mn) * SC2);
            m_run[r] = mn;
            l_lane[r] *= corr;
            #pragma unroll
            for (int dt = 0; dt < 4; ++dt) accO[dt][r] *= corr;
        }
    }

    #pragma unroll
    for (int r = 0; r < 4; ++r) {
        float base = m_run[r] * SC2;
        float ps = 0.f;
        #pragma unroll
        for (int f = 0; f < 4; ++f) {
            float p = exp2f(__builtin_fmaf(s[f][r], SC2, -base));
            pw[(quad * 4 + r) * 68 + f * 16 + col] = p;
            ps += p;
        }
        l_lane[r] += ps;
    }

    // P A-fragments from LDS (same-wave DS ops are in-order; no barrier needed)
    bf16x8 pa[2];
    #pragma unroll
    for (int ks = 0; ks < 2; ++ks) {
        float4 lo = *(const float4*)&pw[col * 68 + ks * 32 + quad * 8];
        float4 hi = *(const float4*)&pw[col * 68 + ks * 32 + quad * 8 + 4];
        union { bf16x8 v; unsigned int u[4]; } pk;
        asm("v_cvt_pk_bf16_f32 %0, %1, %2" : "=v"(pk.u[0]) : "v"(lo.x), "v"(lo.y));
        asm("v_cvt_pk_bf16_f32 %0, %1, %2" : "=v"(pk.u[1]) : "v"(lo.z), "v"(lo.w));
        asm("v_cvt_pk_bf16_f32 %0, %1, %2" : "=v"(pk.u[2]) : "v"(hi.x), "v"(hi.y));
        asm("v_cvt_pk_bf16_f32 %0, %1, %2" : "=v"(pk.u[3]) : "v"(hi.z), "v"(hi.w));
        pa[ks] = pk.v;
    }
    const unsigned short* vp = vbase + (size_t)col * TT + j0 + quad * 8;
    __builtin_amdgcn_s_setprio(1);
    #pragma unroll
    for (int dt = 0; dt < 4; ++dt) {
        bf16x8 v0 = *(const bf16x8*)(vp + (size_t)dt * 16 * TT);
        bf16x8 v1 = *(const bf16x8*)(vp + (size_t)dt * 16 * TT + 32);
        accO[dt] = MFMA(pa[0], v0, accO[dt], 0, 0, 0);
        accO[dt] = MFMA(pa[1], v1, accO[dt], 0, 0, 0);
    }
    __builtin_amdgcn_s_setprio(0);
}

__global__ __launch_bounds__(256) void k_attn(const unsigned short* __restrict__ Q,
                                              const unsigned short* __restrict__ K,
                                              const unsigned short* __restrict__ Vt,
                                              unsigned short* __restrict__ AO) {
    __shared__ float plds[4][16 * 68];
    const int wave = threadIdx.x >> 6, lane = threadIdx.x & 63;
    const int quad = lane >> 4, col = lane & 15;
    // bijective XCD swizzle: 768 blocks = 8 XCDs x 96; each XCD gets one KV panel
    const int lbid = (blockIdx.x & 7) * 96 + (blockIdx.x >> 3);
    const int qb = lbid & 31, bh = lbid >> 5;
    const int h = bh % HH, b = bh / HH;
    const int hkv = h / 3;
    const int i0 = qb * 64 + wave * 16;

    const unsigned short* qbase = Q + ((size_t)(b * HH + h) * TT + i0 + col) * DH + quad * 8;
    bf16x8 qf0 = *(const bf16x8*)qbase;
    bf16x8 qf1 = *(const bf16x8*)(qbase + 32);
    const unsigned short* kbase = K + (size_t)(b * HKV + hkv) * TT * DH;
    const unsigned short* vbase = Vt + (size_t)(b * HKV + hkv) * DH * TT;

    float m_run[4] = {-1e30f, -1e30f, -1e30f, -1e30f};
    float l_lane[4] = {0.f, 0.f, 0.f, 0.f};
    f32x4 accO[4];
    #pragma unroll
    for (int dt = 0; dt < 4; ++dt) accO[dt] = f32x4{0.f, 0.f, 0.f, 0.f};
    float* pw = plds[wave];

    // global tile j in [0,64): global condition true for all; mask = causal only
    if (i0 >= 64)
        attn_tile<0>(0, i0, quad, col, kbase, vbase, qf0, qf1, pw, m_run, l_lane, accO);
    else
        attn_tile<1>(0, i0, quad, col, kbase, vbase, qf0, qf1, pw, m_run, l_lane, accO);

    // window tiles j >= 64
    int jw0 = (i0 - WIN + 1) & ~63;
    if (jw0 < 64) jw0 = 64;
    const int jlast = (i0 + 15) & ~63;
    for (int j0 = jw0; j0 <= jlast; j0 += 64) {
        bool needm = (j0 + 63 > i0) || (j0 <= i0 + 15 - WIN);
        if (needm)
            attn_tile<2>(j0, i0, quad, col, kbase, vbase, qf0, qf1, pw, m_run, l_lane, accO);
        else
            attn_tile<0>(j0, i0, quad, col, kbase, vbase, qf0, qf1, pw, m_run, l_lane, accO);
    }

    float inv[4];
    #pragma unroll
    for (int r = 0; r < 4; ++r) {
        float lt = l_lane[r];
        lt += __shfl_xor(lt, 1);
        lt += __shfl_xor(lt, 2);
        lt += __shfl_xor(lt, 4);
        lt += __shfl_xor(lt, 8);
        inv[r] = 1.0f / lt;
    }
    #pragma unroll
    for (int dt = 0; dt < 4; ++dt)
        #pragma unroll
        for (int r = 0; r < 4; ++r) {
            int t = i0 + quad * 4 + r;
            AO[((size_t)b * TT + t) * DM + h * DH + dt * 16 + col] = f2b(accO[dt][r] * inv[r]);
        }
}

extern "C" void kernel_launch(void* const* d_in, const int* in_sizes, int n_in,
                              void* d_out, int out_size, void* d_ws, size_t ws_size,
                              hipStream_t stream) {
    const float* x  = (const float*)d_in[0];
    const float* wq = (const float*)d_in[1];
    const float* wk = (const float*)d_in[2];
    const float* wv = (const float*)d_in[3];
    const float* wo = (const float*)d_in[4];
    float* out = (float*)d_out;

    char* ws = (char*)d_ws;
    size_t off = 0;
    auto alloc = [&](size_t bytes) -> void* {
        void* p = ws + off;
        off += (bytes + 255) & ~(size_t)255;
        return p;
    };
    const int M = BB * TT; // 4096
    unsigned short* xb  = (unsigned short*)alloc((size_t)M * DM * 2);
    unsigned short* wqT = (unsigned short*)alloc((size_t)DM * DM * 2);
    unsigned short* wkT = (unsigned short*)alloc((size_t)(HKV * DH) * DM * 2);
    unsigned short* wvT = (unsigned short*)alloc((size_t)(HKV * DH) * DM * 2);
    unsigned short* woT = (unsigned short*)alloc((size_t)DM * DM * 2);
    unsigned short* qb  = (unsigned short*)alloc((size_t)BB * HH * TT * DH * 2);
    unsigned short* kb  = (unsigned short*)alloc((size_t)BB * HKV * TT * DH * 2);
    unsigned short* vtb = (unsigned short*)alloc((size_t)BB * HKV * DH * TT * 2);
    unsigned short* ao  = (unsigned short*)alloc((size_t)M * DM * 2);
    float2* rope        = (float2*)alloc((size_t)TT * 32 * sizeof(float2));

    k_prep<<<3328, 256, 0, stream>>>(x, xb, rope);
    k_tw<<<1536, 256, 0, stream>>>(wq, wk, wv, wo, wqT, wkT, wvT, woT);
    k_qkv<<<dim3(M / 128, 20), 256, 0, stream>>>(xb, wqT, wkT, wvT, qb, kb, vtb, rope);
    k_attn<<<768, 256, 0, stream>>>(qb, kb, vtb, ao);
    k_out<<<dim3(M / 128, 12), 256, 0, stream>>>(ao, woT, out);
}